// Round 1
// baseline (789.079 us; speedup 1.0000x reference)
//
#include <hip/hip_runtime.h>
#include <math.h>

// ---------------------------------------------------------------------------
// ISTFTHead: h = x@W + b ; Sr/Si = activation(h) ; frames = [Sr|Si] @ DFTbasis
// (irfft + hann window + 1/N folded into basis) ; overlap-add + env divide.
//
// Shapes: x (16384,512) f32, W (512,1026) f32, b (1026) f32.
// out: (8, 524288) f32.
//
// Workspace layout (bytes):
//   [0,            69206016)  h   (16384 x 1056 f32)   -- later aliased by frames (16384x1024)
//   [69206016,    138412032)  A2  (16384 x 1056 f32)   = [Sr(513) pad(15) Si(513) pad(15)]
//   [138412032,   142737408)  B2  (1056 x 1024 f32)    = [coef*cos*win/N ; 0 ; -coef*sin*win/N ; 0]
// ---------------------------------------------------------------------------

#define BM 128
#define BN 128
#define BK 8

#define TWO_PI_OVER_1024 0.006135923151542565f

__device__ __forceinline__ float hannf(int s) {
    return 0.5f * (1.0f - cosf(TWO_PI_OVER_1024 * (float)s));
}

// Generic fp32 GEMM: C[M x N] = A[M x K] @ B[K x N] (+ bias). Row-major.
// M must be a multiple of BM; K a multiple of BK. N bounds-checked.
// B_VEC: B rows are float4-aligned (ldb % 4 == 0) and N % BN == 0.
template<bool B_VEC, bool BIAS>
__global__ __launch_bounds__(256, 2)
void gemm_f32(const float* __restrict__ A, const float* __restrict__ B,
              const float* __restrict__ bias, float* __restrict__ C,
              int N, int K, int lda, int ldb, int ldc)
{
    __shared__ float As[BK][BM];   // transposed: As[k][m]
    __shared__ float Bs[BK][BN];

    const int t  = threadIdx.x;
    const int m0 = blockIdx.y * BM;
    const int n0 = blockIdx.x * BN;
    const int tm = (t >> 4) * 4;   // 0..60 step 4
    const int tn = (t & 15) * 4;   // 0..60 step 4

    float acc[8][8];
#pragma unroll
    for (int i = 0; i < 8; ++i)
#pragma unroll
        for (int j = 0; j < 8; ++j) acc[i][j] = 0.0f;

    const int a_row = t >> 1;          // 0..127
    const int a_k4  = (t & 1) << 2;    // 0 or 4
    const int b_kr  = t >> 5;          // 0..7
    const int b_nn  = (t & 31) << 2;   // 0..124

    const float* Ap = A + (size_t)(m0 + a_row) * lda + a_k4;

    for (int k0 = 0; k0 < K; k0 += BK) {
        // global loads into registers (before barrier so they overlap compute)
        float4 av = *(const float4*)(Ap + k0);
        float4 bv;
        if (B_VEC) {
            bv = *(const float4*)(B + (size_t)(k0 + b_kr) * ldb + n0 + b_nn);
        } else {
            const float* bp = B + (size_t)(k0 + b_kr) * ldb + n0 + b_nn;
            bv.x = (n0 + b_nn + 0 < N) ? bp[0] : 0.0f;
            bv.y = (n0 + b_nn + 1 < N) ? bp[1] : 0.0f;
            bv.z = (n0 + b_nn + 2 < N) ? bp[2] : 0.0f;
            bv.w = (n0 + b_nn + 3 < N) ? bp[3] : 0.0f;
        }

        __syncthreads();  // previous iteration's LDS reads complete
        As[a_k4 + 0][a_row] = av.x;
        As[a_k4 + 1][a_row] = av.y;
        As[a_k4 + 2][a_row] = av.z;
        As[a_k4 + 3][a_row] = av.w;
        *(float4*)&Bs[b_kr][b_nn] = bv;
        __syncthreads();

#pragma unroll
        for (int kk = 0; kk < BK; ++kk) {
            float4 a0 = *(const float4*)&As[kk][tm];
            float4 a1 = *(const float4*)&As[kk][tm + 64];
            float4 b0 = *(const float4*)&Bs[kk][tn];
            float4 b1 = *(const float4*)&Bs[kk][tn + 64];
            float a[8] = {a0.x, a0.y, a0.z, a0.w, a1.x, a1.y, a1.z, a1.w};
            float bb[8] = {b0.x, b0.y, b0.z, b0.w, b1.x, b1.y, b1.z, b1.w};
#pragma unroll
            for (int i = 0; i < 8; ++i)
#pragma unroll
                for (int j = 0; j < 8; ++j)
                    acc[i][j] = fmaf(a[i], bb[j], acc[i][j]);
        }
    }

    // epilogue
#pragma unroll
    for (int ri = 0; ri < 2; ++ri) {
#pragma unroll
        for (int r = 0; r < 4; ++r) {
            const int m = m0 + ri * 64 + tm + r;
            float* crow = C + (size_t)m * ldc;
#pragma unroll
            for (int ci = 0; ci < 2; ++ci) {
                const int n = n0 + ci * 64 + tn;
                float v[4] = {acc[ri * 4 + r][ci * 4 + 0],
                              acc[ri * 4 + r][ci * 4 + 1],
                              acc[ri * 4 + r][ci * 4 + 2],
                              acc[ri * 4 + r][ci * 4 + 3]};
                if (n + 3 < N) {
                    if (BIAS) {
                        v[0] += bias[n + 0]; v[1] += bias[n + 1];
                        v[2] += bias[n + 2]; v[3] += bias[n + 3];
                    }
                    float4 f4 = make_float4(v[0], v[1], v[2], v[3]);
                    *(float4*)(crow + n) = f4;
                } else {
#pragma unroll
                    for (int q = 0; q < 4; ++q) {
                        if (n + q < N)
                            crow[n + q] = v[q] + (BIAS ? bias[n + q] : 0.0f);
                    }
                }
            }
        }
    }
}

// Activation: Sr = min(exp(h[:,j]),100)*cos(h[:,513+j]), Si = ...*sin(...)
// Writes A2 rows of layout [Sr(0..512) zeros(513..527) Si(528..1040) zeros(1041..1055)]
__global__ __launch_bounds__(256)
void act_kernel(const float* __restrict__ h, float* __restrict__ A2)
{
    const int idx = blockIdx.x * 256 + threadIdx.x;  // over 16384*528
    const int m = idx / 528;
    const int j = idx - m * 528;
    float* arow = A2 + (size_t)m * 1056;
    if (j < 513) {
        const float* hrow = h + (size_t)m * 1056;
        const float mag = fminf(expf(hrow[j]), 100.0f);
        const float p   = hrow[513 + j];
        arow[j]       = mag * cosf(p);
        arow[528 + j] = mag * sinf(p);
    } else {
        arow[j]       = 0.0f;
        arow[528 + j] = 0.0f;
    }
}

// DFT basis with hann window, 1/N and bin-coefs folded in.
__global__ __launch_bounds__(256)
void basis_kernel(float* __restrict__ B2)
{
    const int idx = blockIdx.x * 256 + threadIdx.x;  // over 1056*1024
    const int r = idx >> 10;
    const int n = idx & 1023;
    const float win_scaled = hannf(n) * (1.0f / 1024.0f);
    float v = 0.0f;
    if (r < 513) {
        const int k = r;
        const float coef = (k == 0 || k == 512) ? 1.0f : 2.0f;
        const int mI = (k * n) & 1023;  // exact angle reduction mod 2*pi
        v = coef * cosf(TWO_PI_OVER_1024 * (float)mI) * win_scaled;
    } else if (r >= 528 && r < 1041) {
        const int k = r - 528;
        const float coef = (k == 0 || k == 512) ? 1.0f : 2.0f;
        const int mI = (k * n) & 1023;
        v = -coef * sinf(TWO_PI_OVER_1024 * (float)mI) * win_scaled;
    }
    B2[idx] = v;
}

// Overlap-add (gather over <=4 frames) + envelope divide + PAD trim.
__global__ __launch_bounds__(256)
void ola_kernel(const float* __restrict__ frames, float* __restrict__ out)
{
    const int idx = blockIdx.x * 256 + threadIdx.x;  // over 8 * 524288
    const int b = idx >> 19;        // 524288 = 2^19
    const int j = idx & 524287;
    const int n = j + 384;          // padded coordinate

    int t_hi = n >> 8;
    if (t_hi > 2047) t_hi = 2047;
    const int t_lo = (n >= 1023) ? ((n - 1023 + 255) >> 8) : 0;

    float acc = 0.0f, env = 0.0f;
    for (int tt = t_lo; tt <= t_hi; ++tt) {
        const int s = n - (tt << 8);                      // 0..1023
        const float w = hannf(s);
        acc += frames[(((size_t)(b * 2048 + tt)) << 10) + s];
        env += w * w;
    }
    out[idx] = acc / env;
}

extern "C" void kernel_launch(void* const* d_in, const int* in_sizes, int n_in,
                              void* d_out, int out_size, void* d_ws, size_t ws_size,
                              hipStream_t stream)
{
    const float* x = (const float*)d_in[0];   // 16384 x 512
    const float* W = (const float*)d_in[1];   // 512 x 1026
    const float* b = (const float*)d_in[2];   // 1026
    float* out = (float*)d_out;               // 8 x 524288
    char* ws = (char*)d_ws;

    float* h      = (float*)(ws);                         // 16384 x 1056
    float* A2     = (float*)(ws + (size_t)69206016);      // 16384 x 1056
    float* B2     = (float*)(ws + (size_t)138412032);     // 1056 x 1024
    float* frames = (float*)(ws);                         // 16384 x 1024 (aliases h; h dead by then)

    // 1) h = x @ W + b   (M=16384, N=1026, K=512)
    gemm_f32<false, true><<<dim3(9, 128), 256, 0, stream>>>(
        x, W, b, h, 1026, 512, 512, 1026, 1056);

    // 2) activation -> A2 = [Sr | 0 | Si | 0]
    act_kernel<<<(16384 * 528) / 256, 256, 0, stream>>>(h, A2);

    // 3) windowed-irfft basis
    basis_kernel<<<(1056 * 1024) / 256, 256, 0, stream>>>(B2);

    // 4) frames_win = A2 @ B2   (M=16384, N=1024, K=1056)
    gemm_f32<true, false><<<dim3(8, 128), 256, 0, stream>>>(
        A2, B2, nullptr, frames, 1024, 1056, 1056, 1024, 1024);

    // 5) overlap-add + env divide
    ola_kernel<<<out_size / 256, 256, 0, stream>>>(frames, out);
}

// Round 2
// 271.461 us; speedup vs baseline: 2.9068x; 2.9068x over previous
//
#include <hip/hip_runtime.h>
#include <math.h>

// ---------------------------------------------------------------------------
// ISTFTHead on gfx950 — fp16 MFMA path.
//
//  h = x@W + b               -> GEMM1: 3-product fp16 split (xh*Wh + xl*Wh + xh*Wl),
//                               activation (exp/cos/sin) FUSED into epilogue,
//                               writes A2 (= [Sr|Si]) directly in MFMA-swizzled fp16.
//  frames = A2 @ basis       -> GEMM2: single fp16 MFMA (error ~2e-4, threshold 7.6e-3),
//                               basis = irfft+hann+1/N folded, generated in fragment order.
//  overlap-add + env divide  -> gather kernel (unchanged from round 1).
//
// Operand storage format ("fragment order") for mfma_f32_16x16x32_f16:
//   A tile (16m x 32k): elem(lane,j) = A[m = lane&15][k = (lane>>4)*8 + j]
//   B tile (32k x 16n): elem(lane,j) = B[k = (lane>>4)*8 + j][n = lane&15]
//   C/D: row = (lane>>4)*4 + r, col = lane&15
// Tiles are 64 lanes x 8 halfs = 1 KB, stored contiguously in the exact order
// the GEMM stages them with global_load_lds (wave-uniform base + lane*16).
//
// Workspace map (bytes):
//   A2  [0,          35651584)   16384 x 1088 f16, swizzled [mtb128][kt34][mts8][l][j]
//   B2  [35651584,   37879808)   basis,            [nblk8][kt34][nts8][l][j]
//   A1  [37879808,   71434240)   [xh|xl],          [mtb128][kt32][mts8][l][j]
//   B1  [71434240,   73793536)   [Wh;Wl] mag+phase,[bx9][kt32][t8][l][j]
//   frames [37879808, 104988672) 16384 x 1024 f32  (aliases A1/B1 — dead by GEMM2)
// ---------------------------------------------------------------------------

using half8 = __attribute__((ext_vector_type(8))) _Float16;
using f32x4 = __attribute__((ext_vector_type(4))) float;

#define TWO_PI_OVER_1024 0.006135923151542565f

#define OFF_A2 0
#define OFF_B2 35651584UL
#define OFF_A1 37879808UL
#define OFF_B1 71434240UL
#define OFF_FR 37879808UL

__device__ __forceinline__ float hannf(int s) {
    return 0.5f * (1.0f - cosf(TWO_PI_OVER_1024 * (float)s));
}

// async global->LDS, 16B per lane. lds base is wave-uniform; HW adds lane*16.
__device__ __forceinline__ void stage16(const void* g, void* lds) {
    __builtin_amdgcn_global_load_lds(
        (const __attribute__((address_space(1))) void*)g,
        (__attribute__((address_space(3))) void*)lds,
        16, 0, 0);
}

// ---------------- conversion kernels ----------------

// x (16384x512 f32) -> A1 fragment-swizzled fp16 [xh (kt 0..15) | xl (kt 16..31)]
__global__ __launch_bounds__(256)
void conv_x_k(const float* __restrict__ x, _Float16* __restrict__ A1)
{
    const size_t tid = (size_t)blockIdx.x * 256 + threadIdx.x;   // 2,097,152
    const int l   = (int)(tid & 63);
    const size_t f = tid >> 6;
    const int mts = (int)(f & 7);
    const size_t g = f >> 3;
    const int kt  = (int)(g & 31);
    const int mtb = (int)(g >> 5);
    const int m   = mtb * 128 + mts * 16 + (l & 15);
    const int k0  = (kt & 15) * 32 + (l >> 4) * 8;
    const bool hi = (kt < 16);
    const float* xp = x + (size_t)m * 512 + k0;
    const float4 v0 = *(const float4*)xp;
    const float4 v1 = *(const float4*)(xp + 4);
    const float vv[8] = {v0.x, v0.y, v0.z, v0.w, v1.x, v1.y, v1.z, v1.w};
    half8 o;
#pragma unroll
    for (int j = 0; j < 8; ++j) {
        _Float16 h = (_Float16)vv[j];
        o[j] = hi ? h : (_Float16)(vv[j] - (float)h);
    }
    *(half8*)(A1 + tid * 8) = o;
}

// W (512x1026 f32) -> B1 fragment-swizzled fp16, col-space: per bx(0..8),
// tiles 0..3 = mag cols (bx*64..+63), tiles 4..7 = phase cols (513 + same).
// kt 0..15 = Wh rows, kt 16..31 = Wl rows.
__global__ __launch_bounds__(256)
void conv_w_k(const float* __restrict__ W, _Float16* __restrict__ B1)
{
    const int tid = blockIdx.x * 256 + threadIdx.x;              // 147,456
    const int l  = tid & 63;
    const int f  = tid >> 6;
    const int t8 = f & 7;
    const int g  = f >> 3;
    const int kt = g & 31;
    const int bx = g >> 5;
    const int side = t8 >> 2;
    const int nt   = t8 & 3;
    const int c    = bx * 64 + nt * 16 + (l & 15);               // [0,576)
    const int k0   = (kt & 15) * 32 + (l >> 4) * 8;
    const bool hi  = (kt < 16);
    const int wcol = side ? (513 + c) : c;
    half8 o;
#pragma unroll
    for (int j = 0; j < 8; ++j) {
        float v = (c < 513) ? W[(size_t)(k0 + j) * 1026 + wcol] : 0.0f;
        _Float16 h = (_Float16)v;
        o[j] = hi ? h : (_Float16)(v - (float)h);
    }
    *(half8*)(B1 + (size_t)tid * 8) = o;
}

// Windowed irfft basis in fragment order. Basis row space kk in [0,1088):
// kk<544: cos row for bin kk (valid bin<513); kk>=544: -sin row for bin kk-544.
// value = coef * trig(2*pi*((k*n)&1023)/1024) * hann(n)/1024.
__global__ __launch_bounds__(256)
void basis_k(_Float16* __restrict__ B2)
{
    const int tid = blockIdx.x * 256 + threadIdx.x;              // 139,264
    const int l  = tid & 63;
    const int f  = tid >> 6;
    const int t8 = f & 7;
    const int g  = f >> 3;
    const int kt = g % 34;
    const int bx = g / 34;
    const int n  = bx * 128 + t8 * 16 + (l & 15);
    const int kk0 = kt * 32 + (l >> 4) * 8;
    const float win = hannf(n) * (1.0f / 1024.0f);
    half8 o;
#pragma unroll
    for (int j = 0; j < 8; ++j) {
        const int kk = kk0 + j;
        float v = 0.0f;
        if (kk < 544) {
            const int k = kk;
            if (k < 513) {
                const float coef = (k == 0 || k == 512) ? 1.0f : 2.0f;
                v = coef * cosf(TWO_PI_OVER_1024 * (float)((k * n) & 1023)) * win;
            }
        } else {
            const int k = kk - 544;
            if (k < 513) {
                const float coef = (k == 0 || k == 512) ? 1.0f : 2.0f;
                v = -coef * sinf(TWO_PI_OVER_1024 * (float)((k * n) & 1023)) * win;
            }
        }
        o[j] = (_Float16)v;
    }
    *(half8*)(B2 + (size_t)tid * 8) = o;
}

// ---------------- GEMM1: x@W + b, fused activation, swizzled A2 output ------

__device__ __forceinline__ void store_a2(_Float16* __restrict__ A2, int m, int k, float v)
{
    const int mt2 = m >> 4, mr = m & 15;
    const int kt2 = k >> 5, kc = k & 31;
    const int l2 = (kc >> 3) * 16 + mr;
    const int j2 = kc & 7;
    const int mtb = mt2 >> 3, mts = mt2 & 7;
    const size_t idx = ((((size_t)mtb * 34 + kt2) * 8 + mts) * 64 + l2) * 8 + j2;
    A2[idx] = (_Float16)v;
}

__global__ __launch_bounds__(256, 3)
void gemm1_k(const _Float16* __restrict__ A, const _Float16* __restrict__ B,
             const float* __restrict__ bias, _Float16* __restrict__ A2)
{
    __shared__ _Float16 As[8 * 512];
    __shared__ _Float16 Bs[8 * 512];
    const int t = threadIdx.x, w = t >> 6, l = t & 63;
    const int mblk = blockIdx.y, bx = blockIdx.x;

    f32x4 acc[2][8];
#pragma unroll
    for (int i = 0; i < 2; ++i)
#pragma unroll
        for (int j = 0; j < 8; ++j) acc[i][j] = (f32x4)0.0f;

    const _Float16* Ab = A + (size_t)mblk * (32 * 4096);
    const _Float16* Bb = B + (size_t)bx * (32 * 4096);
    const int lane16 = l * 8;

    for (int step = 0; step < 48; ++step) {
        const int seg = step >> 4, kt = step & 15;
        const int akt = (seg == 1) ? 16 + kt : kt;
        const int bkt = (seg == 2) ? 16 + kt : kt;
        const _Float16* Ag = Ab + (size_t)akt * 4096 + (2 * w) * 512 + lane16;
        const _Float16* Bg = Bb + (size_t)bkt * 4096 + (2 * w) * 512 + lane16;
        __syncthreads();
        stage16(Ag,       &As[(2 * w) * 512]);
        stage16(Ag + 512, &As[(2 * w + 1) * 512]);
        stage16(Bg,       &Bs[(2 * w) * 512]);
        stage16(Bg + 512, &Bs[(2 * w + 1) * 512]);
        __syncthreads();

        half8 a[2], b[8];
#pragma unroll
        for (int i = 0; i < 2; ++i) a[i] = *(const half8*)&As[(2 * w + i) * 512 + lane16];
#pragma unroll
        for (int j = 0; j < 8; ++j) b[j] = *(const half8*)&Bs[j * 512 + lane16];
#pragma unroll
        for (int i = 0; i < 2; ++i)
#pragma unroll
            for (int j = 0; j < 8; ++j)
                acc[i][j] = __builtin_amdgcn_mfma_f32_16x16x32_f16(a[i], b[j], acc[i][j], 0, 0, 0);
    }

    // epilogue: activation + swizzled fp16 stores
    const int r4 = (l >> 4) * 4, c16 = l & 15;
#pragma unroll
    for (int mt = 0; mt < 2; ++mt) {
        const int mbase = mblk * 128 + (2 * w + mt) * 16 + r4;
#pragma unroll
        for (int nt = 0; nt < 4; ++nt) {
            const int c = bx * 64 + nt * 16 + c16;
            const bool valid = (c < 513);
            const float bm = valid ? bias[c] : 0.0f;
            const float bp = valid ? bias[513 + c] : 0.0f;
#pragma unroll
            for (int r = 0; r < 4; ++r) {
                float Sr = 0.0f, Si = 0.0f;
                if (valid) {
                    const float mag = fminf(expf(acc[mt][nt][r] + bm), 100.0f);
                    const float ph  = acc[mt][nt + 4][r] + bp;
                    Sr = mag * cosf(ph);
                    Si = mag * sinf(ph);
                }
                if (c < 544) {
                    store_a2(A2, mbase + r, c, Sr);
                    store_a2(A2, mbase + r, 544 + c, Si);
                }
            }
        }
    }
}

// ---------------- GEMM2: frames = A2 @ basis --------------------------------

__global__ __launch_bounds__(256, 3)
void gemm2_k(const _Float16* __restrict__ A, const _Float16* __restrict__ B,
             float* __restrict__ C)
{
    __shared__ _Float16 As[8 * 512];
    __shared__ _Float16 Bs[8 * 512];
    const int t = threadIdx.x, w = t >> 6, l = t & 63;
    const int mblk = blockIdx.y, nblk = blockIdx.x;
    const int wm = (w & 1) * 4, wn = (w >> 1) * 4;

    f32x4 acc[4][4];
#pragma unroll
    for (int i = 0; i < 4; ++i)
#pragma unroll
        for (int j = 0; j < 4; ++j) acc[i][j] = (f32x4)0.0f;

    const _Float16* Ab = A + (size_t)mblk * (34 * 4096);
    const _Float16* Bb = B + (size_t)nblk * (34 * 4096);
    const int lane16 = l * 8;

    for (int kt = 0; kt < 34; ++kt) {
        const _Float16* Ag = Ab + (size_t)kt * 4096 + (2 * w) * 512 + lane16;
        const _Float16* Bg = Bb + (size_t)kt * 4096 + (2 * w) * 512 + lane16;
        __syncthreads();
        stage16(Ag,       &As[(2 * w) * 512]);
        stage16(Ag + 512, &As[(2 * w + 1) * 512]);
        stage16(Bg,       &Bs[(2 * w) * 512]);
        stage16(Bg + 512, &Bs[(2 * w + 1) * 512]);
        __syncthreads();

        half8 a[4], b[4];
#pragma unroll
        for (int i = 0; i < 4; ++i) a[i] = *(const half8*)&As[(wm + i) * 512 + lane16];
#pragma unroll
        for (int j = 0; j < 4; ++j) b[j] = *(const half8*)&Bs[(wn + j) * 512 + lane16];
#pragma unroll
        for (int i = 0; i < 4; ++i)
#pragma unroll
            for (int j = 0; j < 4; ++j)
                acc[i][j] = __builtin_amdgcn_mfma_f32_16x16x32_f16(a[i], b[j], acc[i][j], 0, 0, 0);
    }

    const int r4 = (l >> 4) * 4, c0 = l & 15;
#pragma unroll
    for (int i = 0; i < 4; ++i) {
        const int m = mblk * 128 + (wm + i) * 16 + r4;
#pragma unroll
        for (int j = 0; j < 4; ++j) {
            const int n = nblk * 128 + (wn + j) * 16 + c0;
#pragma unroll
            for (int r = 0; r < 4; ++r)
                C[(size_t)(m + r) * 1024 + n] = acc[i][j][r];
        }
    }
}

// ---------------- overlap-add + envelope ------------------------------------

__global__ __launch_bounds__(256)
void ola_kernel(const float* __restrict__ frames, float* __restrict__ out)
{
    const int idx = blockIdx.x * 256 + threadIdx.x;   // over 8 * 524288
    const int b = idx >> 19;
    const int j = idx & 524287;
    const int n = j + 384;

    int t_hi = n >> 8;
    if (t_hi > 2047) t_hi = 2047;
    const int t_lo = (n >= 1023) ? ((n - 1023 + 255) >> 8) : 0;

    float acc = 0.0f, env = 0.0f;
    for (int tt = t_lo; tt <= t_hi; ++tt) {
        const int s = n - (tt << 8);
        const float wv = hannf(s);
        acc += frames[(((size_t)(b * 2048 + tt)) << 10) + s];
        env += wv * wv;
    }
    out[idx] = acc / env;
}

// ---------------- launch ----------------------------------------------------

extern "C" void kernel_launch(void* const* d_in, const int* in_sizes, int n_in,
                              void* d_out, int out_size, void* d_ws, size_t ws_size,
                              hipStream_t stream)
{
    const float* x = (const float*)d_in[0];   // 16384 x 512
    const float* W = (const float*)d_in[1];   // 512 x 1026
    const float* b = (const float*)d_in[2];   // 1026
    float* out = (float*)d_out;               // 8 x 524288
    char* ws = (char*)d_ws;

    _Float16* A2 = (_Float16*)(ws + OFF_A2);
    _Float16* B2 = (_Float16*)(ws + OFF_B2);
    _Float16* A1 = (_Float16*)(ws + OFF_A1);
    _Float16* B1 = (_Float16*)(ws + OFF_B1);
    float* frames = (float*)(ws + OFF_FR);

    conv_x_k<<<8192, 256, 0, stream>>>(x, A1);
    conv_w_k<<<576, 256, 0, stream>>>(W, B1);
    basis_k<<<544, 256, 0, stream>>>(B2);

    gemm1_k<<<dim3(9, 128), 256, 0, stream>>>(A1, B1, b, A2);
    gemm2_k<<<dim3(8, 128), 256, 0, stream>>>(A2, B2, frames);

    ola_kernel<<<out_size / 256, 256, 0, stream>>>(frames, out);
}

// Round 3
// 232.239 us; speedup vs baseline: 3.3977x; 1.1689x over previous
//
#include <hip/hip_runtime.h>
#include <math.h>

// ---------------------------------------------------------------------------
// ISTFTHead on gfx950 — fp16 MFMA path, round 3.
//
// Changes vs round 2:
//  * XCD-aware block swizzle in both GEMMs: each XCD owns a contiguous set of
//    mblks, so each A-panel is fetched into exactly one XCD's L2 (round-2
//    FETCH_SIZE showed 222 MB vs 36 MB unique -> cross-XCD duplication).
//  * GEMM1 K-loop restructured: per barrier, stage xh/xl/Wh/Wl (32 KB) and
//    issue all 3 split products into the same accumulators (192 MFMAs per
//    barrier vs 64; staging bytes -33%; 16 barriers vs 48).
//  * GEMM2 unrolls 2 k-tiles per barrier (128 MFMAs/barrier).
//  * frames stored as fp16 (halves gemm2 write + OLA read traffic).
//
// Fragment order for mfma_f32_16x16x32_f16 (verified round 2):
//   A tile: elem(lane,j) = A[m = lane&15][k = (lane>>4)*8 + j]
//   B tile: elem(lane,j) = B[k = (lane>>4)*8 + j][n = lane&15]
//   C/D:    row = (lane>>4)*4 + r, col = lane&15
//
// Workspace map (bytes):
//   A2  [0,          35651584)   16384 x 1088 f16, [mblk128][kt34][mts8][l][j]
//   B2  [35651584,   37879808)   basis,            [nblk8][kt34][nts8][l][j]
//   A1  [37879808,   71434240)   [xh|xl],          [mblk128][kt32][mts8][l][j]
//   B1  [71434240,   73793536)   [Wh;Wl],          [bx9][kt32][t8][l][j]
//   frames [37879808, 71434240)  16384 x 1024 f16  (aliases A1 — dead by GEMM2)
// ---------------------------------------------------------------------------

using half8 = __attribute__((ext_vector_type(8))) _Float16;
using f32x4 = __attribute__((ext_vector_type(4))) float;

#define TWO_PI_OVER_1024 0.006135923151542565f

#define OFF_A2 0
#define OFF_B2 35651584UL
#define OFF_A1 37879808UL
#define OFF_B1 71434240UL
#define OFF_FR 37879808UL

__device__ __forceinline__ float hannf(int s) {
    return 0.5f * (1.0f - cosf(TWO_PI_OVER_1024 * (float)s));
}

// async global->LDS, 16B per lane. Global addr is per-lane (base + lane*16);
// LDS dest is the wave-uniform base (HW adds lane*16).
__device__ __forceinline__ void stage16(const void* g, void* lds) {
    __builtin_amdgcn_global_load_lds(
        (const __attribute__((address_space(1))) void*)g,
        (__attribute__((address_space(3))) void*)lds,
        16, 0, 0);
}

// ---------------- conversion kernels ----------------

// x (16384x512 f32) -> A1 fragment-swizzled fp16 [xh (kt 0..15) | xl (kt 16..31)]
__global__ __launch_bounds__(256)
void conv_x_k(const float* __restrict__ x, _Float16* __restrict__ A1)
{
    const size_t tid = (size_t)blockIdx.x * 256 + threadIdx.x;   // 2,097,152
    const int l   = (int)(tid & 63);
    const size_t f = tid >> 6;
    const int mts = (int)(f & 7);
    const size_t g = f >> 3;
    const int kt  = (int)(g & 31);
    const int mtb = (int)(g >> 5);
    const int m   = mtb * 128 + mts * 16 + (l & 15);
    const int k0  = (kt & 15) * 32 + (l >> 4) * 8;
    const bool hi = (kt < 16);
    const float* xp = x + (size_t)m * 512 + k0;
    const float4 v0 = *(const float4*)xp;
    const float4 v1 = *(const float4*)(xp + 4);
    const float vv[8] = {v0.x, v0.y, v0.z, v0.w, v1.x, v1.y, v1.z, v1.w};
    half8 o;
#pragma unroll
    for (int j = 0; j < 8; ++j) {
        _Float16 h = (_Float16)vv[j];
        o[j] = hi ? h : (_Float16)(vv[j] - (float)h);
    }
    *(half8*)(A1 + tid * 8) = o;
}

// W (512x1026 f32) -> B1 fragment-swizzled fp16, per bx(0..8):
// tiles 0..3 = mag cols (bx*64..+63), tiles 4..7 = phase cols (513 + same).
// kt 0..15 = Wh rows, kt 16..31 = Wl rows.
__global__ __launch_bounds__(256)
void conv_w_k(const float* __restrict__ W, _Float16* __restrict__ B1)
{
    const int tid = blockIdx.x * 256 + threadIdx.x;              // 147,456
    const int l  = tid & 63;
    const int f  = tid >> 6;
    const int t8 = f & 7;
    const int g  = f >> 3;
    const int kt = g & 31;
    const int bx = g >> 5;
    const int side = t8 >> 2;
    const int nt   = t8 & 3;
    const int c    = bx * 64 + nt * 16 + (l & 15);               // [0,576)
    const int k0   = (kt & 15) * 32 + (l >> 4) * 8;
    const bool hi  = (kt < 16);
    const int wcol = side ? (513 + c) : c;
    half8 o;
#pragma unroll
    for (int j = 0; j < 8; ++j) {
        float v = (c < 513) ? W[(size_t)(k0 + j) * 1026 + wcol] : 0.0f;
        _Float16 h = (_Float16)v;
        o[j] = hi ? h : (_Float16)(v - (float)h);
    }
    *(half8*)(B1 + (size_t)tid * 8) = o;
}

// Windowed irfft basis in fragment order. Basis row space kk in [0,1088):
// kk<544: cos row for bin kk; kk>=544: -sin row for bin kk-544.
__global__ __launch_bounds__(256)
void basis_k(_Float16* __restrict__ B2)
{
    const int tid = blockIdx.x * 256 + threadIdx.x;              // 139,264
    const int l  = tid & 63;
    const int f  = tid >> 6;
    const int t8 = f & 7;
    const int g  = f >> 3;
    const int kt = g % 34;
    const int bx = g / 34;
    const int n  = bx * 128 + t8 * 16 + (l & 15);
    const int kk0 = kt * 32 + (l >> 4) * 8;
    const float win = hannf(n) * (1.0f / 1024.0f);
    half8 o;
#pragma unroll
    for (int j = 0; j < 8; ++j) {
        const int kk = kk0 + j;
        float v = 0.0f;
        if (kk < 544) {
            const int k = kk;
            if (k < 513) {
                const float coef = (k == 0 || k == 512) ? 1.0f : 2.0f;
                v = coef * cosf(TWO_PI_OVER_1024 * (float)((k * n) & 1023)) * win;
            }
        } else {
            const int k = kk - 544;
            if (k < 513) {
                const float coef = (k == 0 || k == 512) ? 1.0f : 2.0f;
                v = -coef * sinf(TWO_PI_OVER_1024 * (float)((k * n) & 1023)) * win;
            }
        }
        o[j] = (_Float16)v;
    }
    *(half8*)(B2 + (size_t)tid * 8) = o;
}

// ---------------- GEMM1: x@W + b, fused activation, swizzled A2 output ------

__device__ __forceinline__ void store_a2(_Float16* __restrict__ A2, int m, int k, float v)
{
    const int mt2 = m >> 4, mr = m & 15;
    const int kt2 = k >> 5, kc = k & 31;
    const int l2 = (kc >> 3) * 16 + mr;
    const int j2 = kc & 7;
    const int mtb = mt2 >> 3, mts = mt2 & 7;
    const size_t idx = ((((size_t)mtb * 34 + kt2) * 8 + mts) * 64 + l2) * 8 + j2;
    A2[idx] = (_Float16)v;
}

__global__ __launch_bounds__(256, 3)
void gemm1_k(const _Float16* __restrict__ A, const _Float16* __restrict__ B,
             const float* __restrict__ bias, _Float16* __restrict__ A2)
{
    __shared__ _Float16 Ash[8 * 512];
    __shared__ _Float16 Asl[8 * 512];
    __shared__ _Float16 Bsh[8 * 512];
    __shared__ _Float16 Bsl[8 * 512];
    const int t = threadIdx.x, w = t >> 6, l = t & 63;

    // XCD-aware swizzle: 1152 blocks, 144 per XCD = 16 mblk x 9 bx.
    const int lin = blockIdx.x;
    const int xcd = lin & 7, slot = lin >> 3;
    const int mblk = xcd * 16 + slot / 9;
    const int bx   = slot % 9;

    f32x4 acc[2][8];
#pragma unroll
    for (int i = 0; i < 2; ++i)
#pragma unroll
        for (int j = 0; j < 8; ++j) acc[i][j] = (f32x4)0.0f;

    const _Float16* Ab = A + (size_t)mblk * (32 * 4096);
    const _Float16* Bb = B + (size_t)bx * (32 * 4096);
    const int lane16 = l * 8;
    const int w2 = 2 * w;

    for (int kt = 0; kt < 16; ++kt) {
        const _Float16* Agh = Ab + (size_t)kt * 4096 + w2 * 512 + lane16;
        const _Float16* Agl = Agh + 16 * 4096;
        const _Float16* Bgh = Bb + (size_t)kt * 4096 + w2 * 512 + lane16;
        const _Float16* Bgl = Bgh + 16 * 4096;
        __syncthreads();
        stage16(Agh,       &Ash[w2 * 512]);
        stage16(Agh + 512, &Ash[(w2 + 1) * 512]);
        stage16(Agl,       &Asl[w2 * 512]);
        stage16(Agl + 512, &Asl[(w2 + 1) * 512]);
        stage16(Bgh,       &Bsh[w2 * 512]);
        stage16(Bgh + 512, &Bsh[(w2 + 1) * 512]);
        stage16(Bgl,       &Bsl[w2 * 512]);
        stage16(Bgl + 512, &Bsl[(w2 + 1) * 512]);
        __syncthreads();

        half8 ah[2], al[2];
#pragma unroll
        for (int i = 0; i < 2; ++i) {
            ah[i] = *(const half8*)&Ash[(w2 + i) * 512 + lane16];
            al[i] = *(const half8*)&Asl[(w2 + i) * 512 + lane16];
        }
#pragma unroll
        for (int j = 0; j < 8; ++j) {
            const half8 bh = *(const half8*)&Bsh[j * 512 + lane16];
            const half8 bl = *(const half8*)&Bsl[j * 512 + lane16];
            acc[0][j] = __builtin_amdgcn_mfma_f32_16x16x32_f16(ah[0], bh, acc[0][j], 0, 0, 0);
            acc[1][j] = __builtin_amdgcn_mfma_f32_16x16x32_f16(ah[1], bh, acc[1][j], 0, 0, 0);
            acc[0][j] = __builtin_amdgcn_mfma_f32_16x16x32_f16(al[0], bh, acc[0][j], 0, 0, 0);
            acc[1][j] = __builtin_amdgcn_mfma_f32_16x16x32_f16(al[1], bh, acc[1][j], 0, 0, 0);
            acc[0][j] = __builtin_amdgcn_mfma_f32_16x16x32_f16(ah[0], bl, acc[0][j], 0, 0, 0);
            acc[1][j] = __builtin_amdgcn_mfma_f32_16x16x32_f16(ah[1], bl, acc[1][j], 0, 0, 0);
        }
    }

    // epilogue: activation + swizzled fp16 stores
    const int r4 = (l >> 4) * 4, c16 = l & 15;
#pragma unroll
    for (int mt = 0; mt < 2; ++mt) {
        const int mbase = mblk * 128 + (w2 + mt) * 16 + r4;
#pragma unroll
        for (int nt = 0; nt < 4; ++nt) {
            const int c = bx * 64 + nt * 16 + c16;
            const bool valid = (c < 513);
            const float bm = valid ? bias[c] : 0.0f;
            const float bp = valid ? bias[513 + c] : 0.0f;
#pragma unroll
            for (int r = 0; r < 4; ++r) {
                float Sr = 0.0f, Si = 0.0f;
                if (valid) {
                    const float mag = fminf(expf(acc[mt][nt][r] + bm), 100.0f);
                    const float ph  = acc[mt][nt + 4][r] + bp;
                    Sr = mag * cosf(ph);
                    Si = mag * sinf(ph);
                }
                if (c < 544) {
                    store_a2(A2, mbase + r, c, Sr);
                    store_a2(A2, mbase + r, 544 + c, Si);
                }
            }
        }
    }
}

// ---------------- GEMM2: frames = A2 @ basis (fp16 out) ---------------------

__global__ __launch_bounds__(256, 3)
void gemm2_k(const _Float16* __restrict__ A, const _Float16* __restrict__ B,
             _Float16* __restrict__ C)
{
    __shared__ _Float16 As[2][8 * 512];
    __shared__ _Float16 Bs[2][8 * 512];
    const int t = threadIdx.x, w = t >> 6, l = t & 63;

    // XCD-aware swizzle: 1024 blocks, 128 per XCD = 16 mblk x 8 nblk.
    const int lin = blockIdx.x;
    const int xcd = lin & 7, slot = lin >> 3;
    const int mblk = xcd * 16 + (slot >> 3);
    const int nblk = slot & 7;

    const int wm = (w & 1) * 4, wn = (w >> 1) * 4;

    f32x4 acc[4][4];
#pragma unroll
    for (int i = 0; i < 4; ++i)
#pragma unroll
        for (int j = 0; j < 4; ++j) acc[i][j] = (f32x4)0.0f;

    const _Float16* Ab = A + (size_t)mblk * (34 * 4096);
    const _Float16* Bb = B + (size_t)nblk * (34 * 4096);
    const int lane16 = l * 8;
    const int w2 = 2 * w;

    for (int step = 0; step < 17; ++step) {
        const int kt0 = 2 * step;
        const _Float16* Ag0 = Ab + (size_t)kt0 * 4096 + w2 * 512 + lane16;
        const _Float16* Bg0 = Bb + (size_t)kt0 * 4096 + w2 * 512 + lane16;
        __syncthreads();
        stage16(Ag0,              &As[0][w2 * 512]);
        stage16(Ag0 + 512,        &As[0][(w2 + 1) * 512]);
        stage16(Ag0 + 4096,       &As[1][w2 * 512]);
        stage16(Ag0 + 4096 + 512, &As[1][(w2 + 1) * 512]);
        stage16(Bg0,              &Bs[0][w2 * 512]);
        stage16(Bg0 + 512,        &Bs[0][(w2 + 1) * 512]);
        stage16(Bg0 + 4096,       &Bs[1][w2 * 512]);
        stage16(Bg0 + 4096 + 512, &Bs[1][(w2 + 1) * 512]);
        __syncthreads();

#pragma unroll
        for (int u = 0; u < 2; ++u) {
            half8 a[4], b[4];
#pragma unroll
            for (int i = 0; i < 4; ++i) a[i] = *(const half8*)&As[u][(wm + i) * 512 + lane16];
#pragma unroll
            for (int j = 0; j < 4; ++j) b[j] = *(const half8*)&Bs[u][(wn + j) * 512 + lane16];
#pragma unroll
            for (int i = 0; i < 4; ++i)
#pragma unroll
                for (int j = 0; j < 4; ++j)
                    acc[i][j] = __builtin_amdgcn_mfma_f32_16x16x32_f16(a[i], b[j], acc[i][j], 0, 0, 0);
        }
    }

    const int r4 = (l >> 4) * 4, c0 = l & 15;
#pragma unroll
    for (int i = 0; i < 4; ++i) {
        const int m = mblk * 128 + (wm + i) * 16 + r4;
#pragma unroll
        for (int j = 0; j < 4; ++j) {
            const int n = nblk * 128 + (wn + j) * 16 + c0;
#pragma unroll
            for (int r = 0; r < 4; ++r)
                C[(size_t)(m + r) * 1024 + n] = (_Float16)acc[i][j][r];
        }
    }
}

// ---------------- overlap-add + envelope ------------------------------------

__global__ __launch_bounds__(256)
void ola_kernel(const _Float16* __restrict__ frames, float* __restrict__ out)
{
    const int idx = blockIdx.x * 256 + threadIdx.x;   // over 8 * 524288
    const int b = idx >> 19;
    const int j = idx & 524287;
    const int n = j + 384;

    int t_hi = n >> 8;
    if (t_hi > 2047) t_hi = 2047;
    const int t_lo = (n >= 1023) ? ((n - 1023 + 255) >> 8) : 0;

    float acc = 0.0f, env = 0.0f;
    for (int tt = t_lo; tt <= t_hi; ++tt) {
        const int s = n - (tt << 8);
        const float wv = hannf(s);
        acc += (float)frames[(((size_t)(b * 2048 + tt)) << 10) + s];
        env += wv * wv;
    }
    out[idx] = acc / env;
}

// ---------------- launch ----------------------------------------------------

extern "C" void kernel_launch(void* const* d_in, const int* in_sizes, int n_in,
                              void* d_out, int out_size, void* d_ws, size_t ws_size,
                              hipStream_t stream)
{
    const float* x = (const float*)d_in[0];   // 16384 x 512
    const float* W = (const float*)d_in[1];   // 512 x 1026
    const float* b = (const float*)d_in[2];   // 1026
    float* out = (float*)d_out;               // 8 x 524288
    char* ws = (char*)d_ws;

    _Float16* A2 = (_Float16*)(ws + OFF_A2);
    _Float16* B2 = (_Float16*)(ws + OFF_B2);
    _Float16* A1 = (_Float16*)(ws + OFF_A1);
    _Float16* B1 = (_Float16*)(ws + OFF_B1);
    _Float16* frames = (_Float16*)(ws + OFF_FR);

    conv_x_k<<<8192, 256, 0, stream>>>(x, A1);
    conv_w_k<<<576, 256, 0, stream>>>(W, B1);
    basis_k<<<544, 256, 0, stream>>>(B2);

    gemm1_k<<<1152, 256, 0, stream>>>(A1, B1, b, A2);
    gemm2_k<<<1024, 256, 0, stream>>>(A2, B2, frames);

    ola_kernel<<<out_size / 256, 256, 0, stream>>>(frames, out);
}